// Round 3
// baseline (702.438 us; speedup 1.0000x reference)
//
#include <hip/hip_runtime.h>

// batch=8, seq=16384, d=256, hidden=32, 14 levels, 10 transforms.
//
// v3 structure:
//   k_up    : 4096 blocks x 16 A0-rows, levels 0..3 in LDS. Computes
//             D[r] = sum_{l=0..3} At_l[r>>l] in LDS (At_0..3 never hit HBM),
//             writes D (67 MB) + A_4 rows (4 MB). Weights bf16-packed in LDS.
//   k_tail  : levels 4..9 (64 blocks) then 10..13 (8 blocks), f32 weights,
//             writes At_4..13 in place (8.4 MB, L2-resident).
//   k_dsum  : S_4[g] = sum_{l=4..13} At_l[ancestor]  (4 MB)
//   k_final : out = Z + D[s>>1] + S_4[s>>5]   (2 pyramid reads, not 14)
//
// P layout (rows of 256 f32): [0..65535]=D; level-l (l>=4) at row
// 73728-(131072>>l); S_4 at rows 73720..77815. Total 77816 rows = 79.7 MB.

__device__ __forceinline__ float gelu_t(float x){
  float t = tanhf(0.7978845608028654f * (x + 0.044715f * x * x * x));
  return 0.5f * x * (1.0f + t);
}

// pack two f32 -> two bf16 (RNE) in one uint: lo16 = bf16(a), hi16 = bf16(b)
__device__ __forceinline__ unsigned pack_bf2(float a, float b){
  unsigned ua = __float_as_uint(a); ua = (ua + 0x7fffu + ((ua >> 16) & 1u)) >> 16;
  unsigned ub = __float_as_uint(b); ub = (ub + 0x7fffu + ((ub >> 16) & 1u)) & 0xffff0000u;
  return ua | ub;
}
// unpack: lo = as_float(u<<16), hi = as_float(u & 0xffff0000)

#define SA 260   // a_s/D_s row stride (f32): 16B-aligned, 4-bank skew
#define WS 130   // packed-weight row stride (uints): 2-bank skew per j

// ---------- kernel 1: fused A0 + levels 0..3 + local down-sum D ----------
__global__ void __launch_bounds__(256) k_up(
    const float* __restrict__ Z, float* __restrict__ P,
    const float* __restrict__ W1, const float* __restrict__ B1,
    const float* __restrict__ W2, const float* __restrict__ B2)
{
  __shared__ __align__(16) float a_s[16 * SA];     // 16.6 KB
  __shared__ __align__(16) float D_s[16 * SA];     // 16.6 KB
  __shared__ __align__(8)  unsigned w1p[32 * WS];  // 16.6 KB  [j][d/2] bf16x2
  __shared__ __align__(8)  unsigned w2p[32 * WS];  // 16.6 KB  [j][d/2] bf16x2
  __shared__ __align__(8)  float hp0[32 * 18];     // 2.3 KB   [j][r] partial/final
  __shared__ __align__(8)  float hp1[32 * 18];     // 2.3 KB
  __shared__ float b1s[32];
  __shared__ float b2s[256];
  const int tid = threadIdx.x;
  const long arow0 = (long)blockIdx.x * 16;

  // stage A_0 = 0.5*(Z[2r]+Z[2r+1]) for 16 rows (covered by level-0 barrier)
  {
    const float* Zb = Z + (arow0 << 9);
    for(int c = tid; c < 1024; c += 256){
      int r = c >> 6, q = (c & 63) << 2;
      float4 x = *(const float4*)(Zb + ((long)r << 9) + q);
      float4 y = *(const float4*)(Zb + ((long)r << 9) + 256 + q);
      float4 o;
      o.x = 0.5f*(x.x+y.x); o.y = 0.5f*(x.y+y.y);
      o.z = 0.5f*(x.z+y.z); o.w = 0.5f*(x.w+y.w);
      *(float4*)&a_s[r * SA + q] = o;
    }
  }

  float4 m0 = make_float4(0,0,0,0), m1 = make_float4(0,0,0,0);
  int nr = 16;
  for(int l = 0; l < 4; l++){                    // t = l (l < 9)
    // write back prev level's pair-means (held in regs across barrier)
    if(l > 0){
      int ntp = 1024 >> l;                       // prev level's task count
      if(tid < ntp){
        int rp = tid >> 6, d0 = (tid & 63) << 2;
        *(float4*)&a_s[rp * SA + d0] = m0;
      }
      if(tid + 256 < ntp){
        int rp = (tid + 256) >> 6, d0 = (tid & 63) << 2;
        *(float4*)&a_s[rp * SA + d0] = m1;
      }
    }
    // stage bf16-packed weights + biases for this level
    const float* W1g = W1 + ((long)l << 13);
    const float* W2g = W2 + ((long)l << 13);
    for(int c = tid; c < 4096; c += 256){
      int j = c & 31, d2 = c >> 5;               // W1 is [d][j]
      w1p[j * WS + d2] = pack_bf2(W1g[d2*64 + j], W1g[d2*64 + 32 + j]);
    }
    for(int c = tid; c < 4096; c += 256){
      int d2 = c & 127, j = c >> 7;              // W2 is [j][d]
      float2 wv = *(const float2*)(W2g + j*256 + 2*d2);
      w2p[j * WS + d2] = pack_bf2(wv.x, wv.y);
    }
    if(tid < 32) b1s[tid] = B1[(l << 5) + tid];
    b2s[tid] = B2[(l << 8) + tid];
    __syncthreads();

    // h-phase: tasks = (row-tile: nr/2) x (jg: 8) x (dhalf: 2) = nr*8
    if(tid < (nr << 3)){
      int dh = tid & 1, jg = (tid >> 1) & 7, rt = tid >> 4;
      int r0 = rt * 2, r1 = r0 + 1;
      float acc[2][4];
      #pragma unroll
      for(int jj = 0; jj < 4; jj++){
        float b = dh ? 0.f : b1s[jg*4 + jj];
        acc[0][jj] = b; acc[1][jj] = b;
      }
      const float4* pa0 = (const float4*)&a_s[r0 * SA];
      const float4* pa1 = (const float4*)&a_s[r1 * SA];
      const int d4b = dh << 5;
      #pragma unroll 4
      for(int dd = 0; dd < 32; dd++){
        int d4 = d4b + dd;
        float4 a0 = pa0[d4], a1 = pa1[d4];
        #pragma unroll
        for(int jj = 0; jj < 4; jj++){
          uint2 u = *(const uint2*)&w1p[(jg*4 + jj) * WS + 2*d4];
          float wa = __uint_as_float(u.x << 16);
          float wb = __uint_as_float(u.x & 0xffff0000u);
          float wc = __uint_as_float(u.y << 16);
          float wd = __uint_as_float(u.y & 0xffff0000u);
          acc[0][jj] += a0.x*wa + a0.y*wb + a0.z*wc + a0.w*wd;
          acc[1][jj] += a1.x*wa + a1.y*wb + a1.z*wc + a1.w*wd;
        }
      }
      float* hp = dh ? hp1 : hp0;
      #pragma unroll
      for(int jj = 0; jj < 4; jj++){
        hp[(jg*4 + jj)*18 + r0] = acc[0][jj];
        hp[(jg*4 + jj)*18 + r1] = acc[1][jj];
      }
    }
    __syncthreads();

    // finalize h = gelu(part0 + part1) into hp0
    {
      int ne = nr << 5;
      for(int e = tid; e < ne; e += 256){
        int r = e >> 5, j = e & 31;
        hp0[j*18 + r] = gelu_t(hp0[j*18 + r] + hp1[j*18 + r]);
      }
    }
    __syncthreads();

    // At-phase: task = (pair rp) x (d4: 64). Accumulate into D_s, compute
    // pair-mean (kept in regs across barrier). Level 3 writes A_4 row.
    const int ntask = (nr >> 1) << 6;
    auto at_body = [&](int task) -> float4 {
      int rp = task >> 6, d0 = (task & 63) << 2;
      float4 acc0 = *(const float4*)&b2s[d0];
      float4 acc1 = acc0;
      #pragma unroll 4
      for(int j = 0; j < 32; j++){
        float2 hh = *(const float2*)&hp0[j*18 + 2*rp];
        uint2 u = *(const uint2*)&w2p[j * WS + (d0 >> 1)];
        float wa = __uint_as_float(u.x << 16);
        float wb = __uint_as_float(u.x & 0xffff0000u);
        float wc = __uint_as_float(u.y << 16);
        float wd = __uint_as_float(u.y & 0xffff0000u);
        acc0.x += hh.x*wa; acc0.y += hh.x*wb; acc0.z += hh.x*wc; acc0.w += hh.x*wd;
        acc1.x += hh.y*wa; acc1.y += hh.y*wb; acc1.z += hh.y*wc; acc1.w += hh.y*wd;
      }
      int r0 = rp*2, r1 = r0 + 1;
      int span = 1 << l;
      for(int i = 0; i < span; i++){
        float* dp = &D_s[((r0 << l) + i) * SA + d0];
        float* dq = &D_s[((r1 << l) + i) * SA + d0];
        if(l == 0){
          *(float4*)dp = acc0;
          *(float4*)dq = acc1;
        }else{
          float4 dv = *(const float4*)dp;
          dv.x += acc0.x; dv.y += acc0.y; dv.z += acc0.z; dv.w += acc0.w;
          *(float4*)dp = dv;
          float4 ev = *(const float4*)dq;
          ev.x += acc1.x; ev.y += acc1.y; ev.z += acc1.z; ev.w += acc1.w;
          *(float4*)dq = ev;
        }
      }
      float4 A0v = *(const float4*)&a_s[r0 * SA + d0];
      float4 A1v = *(const float4*)&a_s[r1 * SA + d0];
      float4 mm;
      mm.x = 0.5f*(A0v.x + acc0.x + A1v.x + acc1.x);
      mm.y = 0.5f*(A0v.y + acc0.y + A1v.y + acc1.y);
      mm.z = 0.5f*(A0v.z + acc0.z + A1v.z + acc1.z);
      mm.w = 0.5f*(A0v.w + acc0.w + A1v.w + acc1.w);
      return mm;
    };
    if(tid < ntask){
      m0 = at_body(tid);
      if(l == 3){                                // single pair -> A_4 row
        int d0 = (tid & 63) << 2;
        *(float4*)(P + (((long)65536 + blockIdx.x) << 8) + d0) = m0;
      }
    }
    if(tid + 256 < ntask) m1 = at_body(tid + 256);   // only level 0
    __syncthreads();
    nr >>= 1;
  }

  // write D to P rows [arow0 .. arow0+16)
  for(int c = tid; c < 1024; c += 256){
    int r = c >> 6, q = (c & 63) << 2;
    *(float4*)(P + ((arow0 + r) << 8) + q) = *(const float4*)&D_s[r * SA + q];
  }
}

// ---------- kernel 2: tail levels [l0..l1] on A_4.., block-local sync ----------
// grid = 8 << ss blocks; block = batch b = blockIdx>>ss, subtree sub.
// Level-l rows live at P row 73728-(131072>>l) + b*(8192>>l) + ...
__global__ void __launch_bounds__(512) k_tail(
    float* __restrict__ P,
    const float* __restrict__ W1, const float* __restrict__ B1,
    const float* __restrict__ W2, const float* __restrict__ B2,
    int l0, int l1, int ss)
{
  __shared__ float h_s[64 * 33];                 // max nbs = 64 (l=4, ss=3)
  __shared__ __align__(16) float w1s[8192];      // [d][j] f32
  __shared__ __align__(16) float w2s[8192];      // [j][d] f32
  const int tid = threadIdx.x;
  const int b   = blockIdx.x >> ss;
  const int sub = blockIdx.x & ((1 << ss) - 1);

  for(int l = l0; l <= l1; l++){
    int t = (l < 9) ? l : 9;
    const float* W1g = W1 + ((long)t << 13);
    const float* B1g = B1 + (t << 5);
    const float* W2g = W2 + ((long)t << 13);
    const float* B2g = B2 + (t << 8);
    for(int c = tid; c < 2048; c += 512){
      *(float4*)&w1s[c << 2] = *(const float4*)(W1g + (c << 2));
      *(float4*)&w2s[c << 2] = *(const float4*)(W2g + (c << 2));
    }
    __syncthreads();

    int nbb = 8192 >> l;
    int nbs = nbb >> ss;
    long rowA = (long)(73728 - (131072 >> l)) + (long)b * nbb + (long)sub * nbs;
    float* A = P + (rowA << 8);

    for(int task = tid; task < (nbs << 3); task += 512){
      int r = task >> 3, j4 = (task & 7) << 2;
      float4 acc = *(const float4*)(B1g + j4);
      const float4* ap = (const float4*)(A + ((long)r << 8));
      #pragma unroll 4
      for(int d4 = 0; d4 < 64; d4++){
        float4 a = ap[d4];
        const float* wr = &w1s[(d4 << 7) + j4];
        float4 w0 = *(const float4*)(wr);
        float4 w1 = *(const float4*)(wr + 32);
        float4 w2 = *(const float4*)(wr + 64);
        float4 w3 = *(const float4*)(wr + 96);
        acc.x += a.x*w0.x + a.y*w1.x + a.z*w2.x + a.w*w3.x;
        acc.y += a.x*w0.y + a.y*w1.y + a.z*w2.y + a.w*w3.y;
        acc.z += a.x*w0.z + a.y*w1.z + a.z*w2.z + a.w*w3.z;
        acc.w += a.x*w0.w + a.y*w1.w + a.z*w2.w + a.w*w3.w;
      }
      int hb = r * 33 + j4;
      h_s[hb+0] = gelu_t(acc.x); h_s[hb+1] = gelu_t(acc.y);
      h_s[hb+2] = gelu_t(acc.z); h_s[hb+3] = gelu_t(acc.w);
    }
    __syncthreads();

    int pairs = nbs >> 1;
    if(pairs){
      long rowN = (long)(73728 - (131072 >> (l+1))) + (long)b * (nbb >> 1) + (long)sub * pairs;
      float* An = P + (rowN << 8);
      for(int task = tid; task < (pairs << 5); task += 512){
        int rp = task >> 5, d8 = (task & 31) << 3;
        int r0 = rp << 1, r1 = r0 | 1;
        float* a0 = A + ((long)r0 << 8) + d8;
        float* a1 = A + ((long)r1 << 8) + d8;
        float4 o0a = *(const float4*)(a0), o0b = *(const float4*)(a0 + 4);
        float4 o1a = *(const float4*)(a1), o1b = *(const float4*)(a1 + 4);
        float acc0[8], acc1[8];
        #pragma unroll
        for(int k = 0; k < 8; k++){ float bb = B2g[d8 + k]; acc0[k] = bb; acc1[k] = bb; }
        #pragma unroll 4
        for(int j = 0; j < 32; j++){
          float h0 = h_s[r0*33 + j], h1 = h_s[r1*33 + j];
          const float* wr = &w2s[(j << 8) + d8];
          float4 wa = *(const float4*)(wr);
          float4 wb = *(const float4*)(wr + 4);
          acc0[0] += h0*wa.x; acc0[1] += h0*wa.y; acc0[2] += h0*wa.z; acc0[3] += h0*wa.w;
          acc0[4] += h0*wb.x; acc0[5] += h0*wb.y; acc0[6] += h0*wb.z; acc0[7] += h0*wb.w;
          acc1[0] += h1*wa.x; acc1[1] += h1*wa.y; acc1[2] += h1*wa.z; acc1[3] += h1*wa.w;
          acc1[4] += h1*wb.x; acc1[5] += h1*wb.y; acc1[6] += h1*wb.z; acc1[7] += h1*wb.w;
        }
        *(float4*)(a0)     = make_float4(acc0[0], acc0[1], acc0[2], acc0[3]);
        *(float4*)(a0 + 4) = make_float4(acc0[4], acc0[5], acc0[6], acc0[7]);
        *(float4*)(a1)     = make_float4(acc1[0], acc1[1], acc1[2], acc1[3]);
        *(float4*)(a1 + 4) = make_float4(acc1[4], acc1[5], acc1[6], acc1[7]);
        float4 ma, mb;
        ma.x = 0.5f*(o0a.x + acc0[0] + o1a.x + acc1[0]);
        ma.y = 0.5f*(o0a.y + acc0[1] + o1a.y + acc1[1]);
        ma.z = 0.5f*(o0a.z + acc0[2] + o1a.z + acc1[2]);
        ma.w = 0.5f*(o0a.w + acc0[3] + o1a.w + acc1[3]);
        mb.x = 0.5f*(o0b.x + acc0[4] + o1b.x + acc1[4]);
        mb.y = 0.5f*(o0b.y + acc0[5] + o1b.y + acc1[5]);
        mb.z = 0.5f*(o0b.z + acc0[6] + o1b.z + acc1[6]);
        mb.w = 0.5f*(o0b.w + acc0[7] + o1b.w + acc1[7]);
        *(float4*)(An + ((long)rp << 8) + d8)     = ma;
        *(float4*)(An + ((long)rp << 8) + d8 + 4) = mb;
      }
    } else if(tid < 32){
      int d8 = tid << 3;
      float acc0[8];
      #pragma unroll
      for(int k = 0; k < 8; k++) acc0[k] = B2g[d8 + k];
      #pragma unroll 4
      for(int j = 0; j < 32; j++){
        float h0 = h_s[j];
        const float* wr = &w2s[(j << 8) + d8];
        float4 wa = *(const float4*)(wr);
        float4 wb = *(const float4*)(wr + 4);
        acc0[0] += h0*wa.x; acc0[1] += h0*wa.y; acc0[2] += h0*wa.z; acc0[3] += h0*wa.w;
        acc0[4] += h0*wb.x; acc0[5] += h0*wb.y; acc0[6] += h0*wb.z; acc0[7] += h0*wb.w;
      }
      *(float4*)(A + d8)     = make_float4(acc0[0], acc0[1], acc0[2], acc0[3]);
      *(float4*)(A + d8 + 4) = make_float4(acc0[4], acc0[5], acc0[6], acc0[7]);
    }
    __syncthreads();
  }
}

// ---------- kernel 3: S_4[g] = sum_{l=4..13} At_l[ancestor(g)] ----------
__global__ void __launch_bounds__(256) k_dsum(float* __restrict__ P){
  long idx = (long)blockIdx.x * 256 + threadIdx.x;   // 262,144 threads
  int g  = (int)(idx >> 6);                          // A_4 row 0..4095
  int d0 = (int)(idx & 63) << 2;
  int b = g >> 9, gb = g & 511;
  float4 acc = make_float4(0.f, 0.f, 0.f, 0.f);
  #pragma unroll
  for(int l = 4; l < 14; l++){
    long row = (long)(73728 - (131072 >> l)) + ((long)b << (13 - l)) + (gb >> (l - 4));
    float4 f = *(const float4*)(P + (row << 8) + d0);
    acc.x += f.x; acc.y += f.y; acc.z += f.z; acc.w += f.w;
  }
  *(float4*)(P + ((long)(73720 + g) << 8) + d0) = acc;
}

// ---------- kernel 4: out = Z + D[s>>1] + S_4[s>>5] ----------
__global__ void __launch_bounds__(256) k_final(const float* __restrict__ Z,
                                               const float* __restrict__ P,
                                               float* __restrict__ out){
  long t = (long)blockIdx.x * 256 + threadIdx.x;
  long base = t * 4;
  long row  = base >> 8;
  int  doff = (int)(base & 255);
  int  b = (int)(row >> 14), s = (int)(row & 16383);
  float4 acc = *(const float4*)(Z + base);
  long drow = ((long)b << 13) + (s >> 1);
  float4 dv = *(const float4*)(P + (drow << 8) + doff);
  long srow = 73720 + ((long)b << 9) + (s >> 5);
  float4 sv = *(const float4*)(P + (srow << 8) + doff);
  acc.x += dv.x + sv.x; acc.y += dv.y + sv.y;
  acc.z += dv.z + sv.z; acc.w += dv.w + sv.w;
  *(float4*)(out + base) = acc;
}

extern "C" void kernel_launch(void* const* d_in, const int* in_sizes, int n_in,
                              void* d_out, int out_size, void* d_ws, size_t ws_size,
                              hipStream_t stream) {
  const float* Z  = (const float*)d_in[0];
  const float* W1 = (const float*)d_in[1];
  const float* B1 = (const float*)d_in[2];
  const float* W2 = (const float*)d_in[3];
  const float* B2 = (const float*)d_in[4];

  const size_t pyr_elems = (size_t)77816 * 256;   // 79.7 MB
  const bool   use_ws    = ws_size >= pyr_elems * sizeof(float);
  float* P = use_ws ? (float*)d_ws : (float*)d_out;

  // levels 0..3 + D down-sum (At_0..3 never hit HBM)
  k_up<<<4096, 256, 0, stream>>>(Z, P, W1, B1, W2, B2);
  // levels 4..9 (8 subtrees per batch), then 10..13 (1 per batch)
  k_tail<<<64, 512, 0, stream>>>(P, W1, B1, W2, B2, 4, 9, 3);
  k_tail<<<8,  512, 0, stream>>>(P, W1, B1, W2, B2, 10, 13, 0);
  // S_4 down-sum of tail levels
  k_dsum<<<1024, 256, 0, stream>>>(P);

  if(use_ws){
    k_final<<<32768, 256, 0, stream>>>(Z, P, (float*)d_out);
  }else{
    // pyramid occupies d_out: accumulate into Z's buffer (harness restores
    // inputs before every launch), then D2D copy
    k_final<<<32768, 256, 0, stream>>>(Z, P, (float*)d_in[0]);
    hipMemcpyAsync(d_out, d_in[0], (size_t)out_size * sizeof(float),
                   hipMemcpyDeviceToDevice, stream);
  }
}

// Round 5
// 526.683 us; speedup vs baseline: 1.3337x; 1.3337x over previous
//
#include <hip/hip_runtime.h>

// batch=8, seq=16384, d=256, hidden=32, 14 levels, 10 transforms, all f32.
//
// Mean-pyramid formulation:
//   A_0[r]     = 0.5*(Z[2r] + Z[2r+1])
//   At_l       = MLP_t(A_l)            (overwrites level-l rows in place)
//   A_{l+1}[g] = 0.5*((A_l+At_l)[2g] + (A_l+At_l)[2g+1])
//   out[b,s]   = Z[b,s] + sum_l At_l[b, s>>(l+1)]
// Pyramid P: level-l rows at offset 131072-(131072>>l); 131064 rows (134.2MB).
//
// v5 = v4 with the HS bug fixed: h-tile row stride must cover 32 rows
// (v4's HS=20 made rows 20..31 of each j collide with rows 0..11 of j+1).
// HS=36: >=32, 16B-aligned, 4-word skew per j.

__device__ __forceinline__ float gelu_t(float x){
  float t = tanhf(0.7978845608028654f * (x + 0.044715f * x * x * x));
  return 0.5f * x * (1.0f + t);
}

#define SA 260   // a_s row stride (f32): 16B-aligned, 4-bank skew per row
#define HS 36    // h_s row stride (f32): >=32 rows, 16B-aligned, 4-bank skew

// ---------- kernel 1: n_lev levels starting at l_base, 32 rows/block ----------
// l_base==0: stage A_0 from Z pairs; else stage A_{l_base} from P.
// Writes At_l for each level and A_{l_base+n_lev} rows at the end.
__global__ void __launch_bounds__(256) k_block(
    const float* __restrict__ Z, float* __restrict__ P,
    const float* __restrict__ W1, const float* __restrict__ B1,
    const float* __restrict__ W2, const float* __restrict__ B2,
    int l_base, int n_lev)
{
  __shared__ __align__(16) float a_s[32 * SA];   // 33.3 KB
  __shared__ __align__(16) float w_s[8192];      // 32 KB union: W1 then W2
  __shared__ __align__(16) float hp0[32 * HS];   // 4.6 KB [j][r], d-half 0 (+bias)
  __shared__ __align__(16) float hp1[32 * HS];   // 4.6 KB [j][r], d-half 1
  __shared__ float b1s[32];
  __shared__ float b2s[256];
  const int tid = threadIdx.x;
  const long g0 = (long)blockIdx.x * 32;         // first level-l_base row

  // stage A_{l_base} (level-0 stage barrier below covers this)
  if(l_base == 0){
    const float* Zb = Z + (g0 << 9);
    for(int c = tid; c < 2048; c += 256){
      int r = c >> 6, q = (c & 63) << 2;
      float4 x = *(const float4*)(Zb + ((long)r << 9) + q);
      float4 y = *(const float4*)(Zb + ((long)r << 9) + 256 + q);
      float4 o;
      o.x = 0.5f*(x.x+y.x); o.y = 0.5f*(x.y+y.y);
      o.z = 0.5f*(x.z+y.z); o.w = 0.5f*(x.w+y.w);
      *(float4*)&a_s[r * SA + q] = o;
    }
  }else{
    const float* Ab = P + (((long)(131072 - (131072 >> l_base)) + g0) << 8);
    for(int c = tid; c < 2048; c += 256){
      int r = c >> 6, q = (c & 63) << 2;
      *(float4*)&a_s[r * SA + q] = *(const float4*)(Ab + ((long)r << 8) + q);
    }
  }

  float4 mA[2], mB[2];
  int ntask_prev = 0;
  int nr = 32;
  for(int i = 0; i < n_lev; i++){
    const int l = l_base + i;                    // t = l (l <= 4 < 9)
    const float* W1g = W1 + ((long)l << 13);
    const float* W2g = W2 + ((long)l << 13);

    // write back prev level's pair-means (held in regs across the barrier)
    if(i > 0){
      #pragma unroll
      for(int it = 0; it < 2; it++){
        int task = tid + (it << 8);
        if(task < ntask_prev){
          int pp = task >> 6, d0 = (task & 63) << 2;
          *(float4*)&a_s[(2*pp    ) * SA + d0] = mA[it];
          *(float4*)&a_s[(2*pp + 1) * SA + d0] = mB[it];
        }
      }
    }
    // stage W1 (natural [d][j], compact) + biases
    for(int c = tid; c < 2048; c += 256)
      *(float4*)&w_s[c << 2] = *(const float4*)(W1g + (c << 2));
    if(tid < 32) b1s[tid] = B1[(l << 5) + tid];
    b2s[tid] = B2[(l << 8) + tid];
    __syncthreads();

    // h-phase: task = (row-pair rt) x (jg:8) x (d-half:2) = nr*8 tasks.
    // Each thread: 2 rows x 4 j x 128 d. w_s reads 2-way aliased (free),
    // a_s reads broadcast across jg + 2-way across dh (free).
    if(tid < (nr << 3)){
      int dh = tid & 1, jg = (tid >> 1) & 7, rt = tid >> 4;
      int r0 = rt * 2, r1 = r0 + 1;
      float acc0[4], acc1[4];
      #pragma unroll
      for(int jj = 0; jj < 4; jj++){
        float b = dh ? 0.f : b1s[jg*4 + jj];
        acc0[jj] = b; acc1[jj] = b;
      }
      const float4* pa0 = (const float4*)&a_s[r0 * SA];
      const float4* pa1 = (const float4*)&a_s[r1 * SA];
      const int db = dh << 5;
      #pragma unroll 4
      for(int dd = 0; dd < 32; dd++){
        int d4 = db + dd;
        float4 a0 = pa0[d4], a1 = pa1[d4];
        const float* wb = &w_s[(d4 << 7) + (jg << 2)];
        float4 w0 = *(const float4*)(wb);
        float4 w1 = *(const float4*)(wb + 32);
        float4 w2 = *(const float4*)(wb + 64);
        float4 w3 = *(const float4*)(wb + 96);
        acc0[0] += a0.x*w0.x + a0.y*w1.x + a0.z*w2.x + a0.w*w3.x;
        acc0[1] += a0.x*w0.y + a0.y*w1.y + a0.z*w2.y + a0.w*w3.y;
        acc0[2] += a0.x*w0.z + a0.y*w1.z + a0.z*w2.z + a0.w*w3.z;
        acc0[3] += a0.x*w0.w + a0.y*w1.w + a0.z*w2.w + a0.w*w3.w;
        acc1[0] += a1.x*w0.x + a1.y*w1.x + a1.z*w2.x + a1.w*w3.x;
        acc1[1] += a1.x*w0.y + a1.y*w1.y + a1.z*w2.y + a1.w*w3.y;
        acc1[2] += a1.x*w0.z + a1.y*w1.z + a1.z*w2.z + a1.w*w3.z;
        acc1[3] += a1.x*w0.w + a1.y*w1.w + a1.z*w2.w + a1.w*w3.w;
      }
      float* hp = dh ? hp1 : hp0;
      #pragma unroll
      for(int jj = 0; jj < 4; jj++){
        hp[(jg*4 + jj)*HS + r0] = acc0[jj];
        hp[(jg*4 + jj)*HS + r1] = acc1[jj];
      }
    }
    __syncthreads();

    // restage w_s with W2 ([j][d] natural) + finalize h = gelu(p0 + p1)
    for(int c = tid; c < 2048; c += 256)
      *(float4*)&w_s[c << 2] = *(const float4*)(W2g + (c << 2));
    for(int e = tid; e < (nr << 5); e += 256){
      int r = e >> 5, j = e & 31;
      hp0[j*HS + r] = gelu_t(hp0[j*HS + r] + hp1[j*HS + r]);
    }
    __syncthreads();

    // At-phase: task = (pair-pair pp) x (d4:64). Each thread: 4 rows x 4 d.
    // h read is wave-broadcast float4; w_s read contiguous 1KB/wave.
    const long Prow  = (long)(131072 - (131072 >> l)) + (g0 >> i);
    const long ProwN = (long)(131072 - (131072 >> (l+1))) + (g0 >> (i+1));
    const int  npp   = nr >> 2;                  // nr in {32,16,8}
    const int  ntask = npp << 6;
    const bool last  = (i == n_lev - 1);
    #pragma unroll
    for(int it = 0; it < 2; it++){
      int task = tid + (it << 8);
      if(task < ntask){
        int pp = task >> 6, d0 = (task & 63) << 2;
        int q0 = pp << 2;
        float4 bb = *(const float4*)&b2s[d0];
        float4 acc0 = bb, acc1 = bb, acc2 = bb, acc3 = bb;
        #pragma unroll 4
        for(int j = 0; j < 32; j++){
          float4 hh = *(const float4*)&hp0[j*HS + q0];
          float4 w  = *(const float4*)&w_s[(j << 8) + d0];
          acc0.x += hh.x*w.x; acc0.y += hh.x*w.y; acc0.z += hh.x*w.z; acc0.w += hh.x*w.w;
          acc1.x += hh.y*w.x; acc1.y += hh.y*w.y; acc1.z += hh.y*w.z; acc1.w += hh.y*w.w;
          acc2.x += hh.z*w.x; acc2.y += hh.z*w.y; acc2.z += hh.z*w.z; acc2.w += hh.z*w.w;
          acc3.x += hh.w*w.x; acc3.y += hh.w*w.y; acc3.z += hh.w*w.z; acc3.w += hh.w*w.w;
        }
        *(float4*)(P + ((Prow + q0    ) << 8) + d0) = acc0;
        *(float4*)(P + ((Prow + q0 + 1) << 8) + d0) = acc1;
        *(float4*)(P + ((Prow + q0 + 2) << 8) + d0) = acc2;
        *(float4*)(P + ((Prow + q0 + 3) << 8) + d0) = acc3;
        float4 A0 = *(const float4*)&a_s[(q0    ) * SA + d0];
        float4 A1 = *(const float4*)&a_s[(q0 + 1) * SA + d0];
        float4 A2 = *(const float4*)&a_s[(q0 + 2) * SA + d0];
        float4 A3 = *(const float4*)&a_s[(q0 + 3) * SA + d0];
        float4 ma, mb;
        ma.x = 0.5f*(A0.x + acc0.x + A1.x + acc1.x);
        ma.y = 0.5f*(A0.y + acc0.y + A1.y + acc1.y);
        ma.z = 0.5f*(A0.z + acc0.z + A1.z + acc1.z);
        ma.w = 0.5f*(A0.w + acc0.w + A1.w + acc1.w);
        mb.x = 0.5f*(A2.x + acc2.x + A3.x + acc3.x);
        mb.y = 0.5f*(A2.y + acc2.y + A3.y + acc3.y);
        mb.z = 0.5f*(A2.z + acc2.z + A3.z + acc3.z);
        mb.w = 0.5f*(A2.w + acc2.w + A3.w + acc3.w);
        mA[it] = ma; mB[it] = mb;
        if(last){
          *(float4*)(P + ((ProwN + 2*pp    ) << 8) + d0) = ma;
          *(float4*)(P + ((ProwN + 2*pp + 1) << 8) + d0) = mb;
        }
      }
    }
    __syncthreads();
    ntask_prev = ntask;
    nr >>= 1;
  }
}

// ---------- kernel 2: tail levels [l0..l1], block-local sync per level ----------
// grid = 8 << ss blocks; block handles batch b = blockIdx>>ss, subtree sub.
__global__ void __launch_bounds__(512) k_tail(
    float* __restrict__ P,
    const float* __restrict__ W1, const float* __restrict__ B1,
    const float* __restrict__ W2, const float* __restrict__ B2,
    int l0, int l1, int ss)
{
  __shared__ float h_s[128 * 33];                // max nbs = 128 (l=5, ss=1)
  __shared__ __align__(16) float w1s[8192];      // [d][j] f32
  __shared__ __align__(16) float w2s[8192];      // [j][d] f32
  const int tid = threadIdx.x;
  const int b   = blockIdx.x >> ss;
  const int sub = blockIdx.x & ((1 << ss) - 1);

  for(int l = l0; l <= l1; l++){
    int t = (l < 9) ? l : 9;
    const float* W1g = W1 + ((long)t << 13);
    const float* B1g = B1 + (t << 5);
    const float* W2g = W2 + ((long)t << 13);
    const float* B2g = B2 + (t << 8);
    for(int c = tid; c < 2048; c += 512){
      *(float4*)&w1s[c << 2] = *(const float4*)(W1g + (c << 2));
      *(float4*)&w2s[c << 2] = *(const float4*)(W2g + (c << 2));
    }
    __syncthreads();

    int nbb = 8192 >> l;
    int nbs = nbb >> ss;
    long rowA = (long)(131072 - (131072 >> l)) + (long)b * nbb + (long)sub * nbs;
    float* A = P + (rowA << 8);

    for(int task = tid; task < (nbs << 3); task += 512){
      int r = task >> 3, j4 = (task & 7) << 2;
      float4 acc = *(const float4*)(B1g + j4);
      const float4* ap = (const float4*)(A + ((long)r << 8));
      #pragma unroll 4
      for(int d4 = 0; d4 < 64; d4++){
        float4 a = ap[d4];
        const float* wr = &w1s[(d4 << 7) + j4];
        float4 w0 = *(const float4*)(wr);
        float4 w1 = *(const float4*)(wr + 32);
        float4 w2 = *(const float4*)(wr + 64);
        float4 w3 = *(const float4*)(wr + 96);
        acc.x += a.x*w0.x + a.y*w1.x + a.z*w2.x + a.w*w3.x;
        acc.y += a.x*w0.y + a.y*w1.y + a.z*w2.y + a.w*w3.y;
        acc.z += a.x*w0.z + a.y*w1.z + a.z*w2.z + a.w*w3.z;
        acc.w += a.x*w0.w + a.y*w1.w + a.z*w2.w + a.w*w3.w;
      }
      int hb = r * 33 + j4;
      h_s[hb+0] = gelu_t(acc.x); h_s[hb+1] = gelu_t(acc.y);
      h_s[hb+2] = gelu_t(acc.z); h_s[hb+3] = gelu_t(acc.w);
    }
    __syncthreads();

    int pairs = nbs >> 1;
    if(pairs){
      long rowN = (long)(131072 - (131072 >> (l+1))) + (long)b * (nbb >> 1) + (long)sub * pairs;
      float* An = P + (rowN << 8);
      for(int task = tid; task < (pairs << 5); task += 512){
        int rp = task >> 5, d8 = (task & 31) << 3;
        int r0 = rp << 1, r1 = r0 | 1;
        float* a0 = A + ((long)r0 << 8) + d8;
        float* a1 = A + ((long)r1 << 8) + d8;
        float4 o0a = *(const float4*)(a0), o0b = *(const float4*)(a0 + 4);
        float4 o1a = *(const float4*)(a1), o1b = *(const float4*)(a1 + 4);
        float acc0[8], acc1[8];
        #pragma unroll
        for(int k = 0; k < 8; k++){ float bb = B2g[d8 + k]; acc0[k] = bb; acc1[k] = bb; }
        #pragma unroll 4
        for(int j = 0; j < 32; j++){
          float h0 = h_s[r0*33 + j], h1 = h_s[r1*33 + j];
          const float* wr = &w2s[(j << 8) + d8];
          float4 wa = *(const float4*)(wr);
          float4 wb = *(const float4*)(wr + 4);
          acc0[0] += h0*wa.x; acc0[1] += h0*wa.y; acc0[2] += h0*wa.z; acc0[3] += h0*wa.w;
          acc0[4] += h0*wb.x; acc0[5] += h0*wb.y; acc0[6] += h0*wb.z; acc0[7] += h0*wb.w;
          acc1[0] += h1*wa.x; acc1[1] += h1*wa.y; acc1[2] += h1*wa.z; acc1[3] += h1*wa.w;
          acc1[4] += h1*wb.x; acc1[5] += h1*wb.y; acc1[6] += h1*wb.z; acc1[7] += h1*wb.w;
        }
        *(float4*)(a0)     = make_float4(acc0[0], acc0[1], acc0[2], acc0[3]);
        *(float4*)(a0 + 4) = make_float4(acc0[4], acc0[5], acc0[6], acc0[7]);
        *(float4*)(a1)     = make_float4(acc1[0], acc1[1], acc1[2], acc1[3]);
        *(float4*)(a1 + 4) = make_float4(acc1[4], acc1[5], acc1[6], acc1[7]);
        float4 ma, mb;
        ma.x = 0.5f*(o0a.x + acc0[0] + o1a.x + acc1[0]);
        ma.y = 0.5f*(o0a.y + acc0[1] + o1a.y + acc1[1]);
        ma.z = 0.5f*(o0a.z + acc0[2] + o1a.z + acc1[2]);
        ma.w = 0.5f*(o0a.w + acc0[3] + o1a.w + acc1[3]);
        mb.x = 0.5f*(o0b.x + acc0[4] + o1b.x + acc1[4]);
        mb.y = 0.5f*(o0b.y + acc0[5] + o1b.y + acc1[5]);
        mb.z = 0.5f*(o0b.z + acc0[6] + o1b.z + acc1[6]);
        mb.w = 0.5f*(o0b.w + acc0[7] + o1b.w + acc1[7]);
        *(float4*)(An + ((long)rp << 8) + d8)     = ma;
        *(float4*)(An + ((long)rp << 8) + d8 + 4) = mb;
      }
    } else if(tid < 32){
      int d8 = tid << 3;
      float acc0[8];
      #pragma unroll
      for(int k = 0; k < 8; k++) acc0[k] = B2g[d8 + k];
      #pragma unroll 4
      for(int j = 0; j < 32; j++){
        float h0 = h_s[j];
        const float* wr = &w2s[(j << 8) + d8];
        float4 wa = *(const float4*)(wr);
        float4 wb = *(const float4*)(wr + 4);
        acc0[0] += h0*wa.x; acc0[1] += h0*wa.y; acc0[2] += h0*wa.z; acc0[3] += h0*wa.w;
        acc0[4] += h0*wb.x; acc0[5] += h0*wb.y; acc0[6] += h0*wb.z; acc0[7] += h0*wb.w;
      }
      *(float4*)(A + d8)     = make_float4(acc0[0], acc0[1], acc0[2], acc0[3]);
      *(float4*)(A + d8 + 4) = make_float4(acc0[4], acc0[5], acc0[6], acc0[7]);
    }
    __syncthreads();
  }
}

// ---------- kernel 3: in-place S5: At_5[g] += sum_{l=6..13} At_l[anc(g)] ----------
// Race-free: each thread RMWs only its own level-5 elements; levels 6..13 are
// read-only here. After this, level-5 rows hold the levels>=5 down-sum.
__global__ void __launch_bounds__(256) k_dsum(float* __restrict__ P){
  long idx = (long)blockIdx.x * 256 + threadIdx.x;   // 2048 rows * 64 float4
  int g  = (int)(idx >> 6);                          // level-5 row 0..2047
  int d0 = (int)(idx & 63) << 2;
  int b = g >> 8, gb = g & 255;
  float4 acc = make_float4(0.f, 0.f, 0.f, 0.f);
  #pragma unroll
  for(int l = 6; l < 14; l++){
    long row = (long)(131072 - (131072 >> l)) + ((long)b << (13 - l)) + (gb >> (l - 5));
    float4 f = *(const float4*)(P + (row << 8) + d0);
    acc.x += f.x; acc.y += f.y; acc.z += f.z; acc.w += f.w;
  }
  float* p5 = P + (((long)126976 + g) << 8) + d0;
  float4 v = *(const float4*)p5;
  v.x += acc.x; v.y += acc.y; v.z += acc.z; v.w += acc.w;
  *(float4*)p5 = v;
}

// ---------- kernel 4: out = Z + sum_{l=0..4} At_l[s>>(l+1)] + S5[s>>6] ----------
__global__ void __launch_bounds__(256) k_final(const float* __restrict__ Z,
                                               const float* __restrict__ P,
                                               float* __restrict__ out){
  long t = (long)blockIdx.x * 256 + threadIdx.x;
  long base = t * 4;
  long row  = base >> 8;
  int  doff = (int)(base & 255);
  int  b = (int)(row >> 14), s = (int)(row & 16383);
  float4 acc = *(const float4*)(Z + base);
  #pragma unroll
  for(int l = 0; l < 6; l++){                        // level 5 holds S5
    int rowoff = 131072 - (131072 >> l);
    int g = s >> (l + 1);
    long p = ((long)(rowoff + (b << (13 - l)) + g) << 8) + doff;
    float4 f = *(const float4*)(P + p);
    acc.x += f.x; acc.y += f.y; acc.z += f.z; acc.w += f.w;
  }
  *(float4*)(out + base) = acc;
}

extern "C" void kernel_launch(void* const* d_in, const int* in_sizes, int n_in,
                              void* d_out, int out_size, void* d_ws, size_t ws_size,
                              hipStream_t stream) {
  const float* Z  = (const float*)d_in[0];
  const float* W1 = (const float*)d_in[1];
  const float* B1 = (const float*)d_in[2];
  const float* W2 = (const float*)d_in[3];
  const float* B2 = (const float*)d_in[4];

  const size_t pyr_elems = 33552384;              // 131064 rows * 256 (134.2MB)
  const bool   use_ws    = ws_size >= pyr_elems * sizeof(float);
  float* P = use_ws ? (float*)d_ws : (float*)d_out;   // fits in d_out too

  // levels 0..1 (77% of MLP FLOPs, all phases full-width)
  k_block<<<2048, 256, 0, stream>>>(Z, P, W1, B1, W2, B2, 0, 2);
  // levels 2..4 (nr = 32/16/8 per block)
  k_block<<<512,  256, 0, stream>>>(Z, P, W1, B1, W2, B2, 2, 3);
  // levels 5..11 (2 subtrees per batch), then 12..13 (1 per batch)
  k_tail<<<16, 512, 0, stream>>>(P, W1, B1, W2, B2, 5, 11, 1);
  k_tail<<<8,  512, 0, stream>>>(P, W1, B1, W2, B2, 12, 13, 0);
  // fold levels 6..13 into level 5 (2MB, L2-resident)
  k_dsum<<<512, 256, 0, stream>>>(P);

  if(use_ws){
    k_final<<<32768, 256, 0, stream>>>(Z, P, (float*)d_out);
  }else{
    // pyramid occupies d_out: accumulate into Z's buffer (harness restores
    // inputs before every launch), then D2D copy
    k_final<<<32768, 256, 0, stream>>>(Z, P, (float*)d_in[0]);
    hipMemcpyAsync(d_out, d_in[0], (size_t)out_size * sizeof(float),
                   hipMemcpyDeviceToDevice, stream);
  }
}